// Round 10
// baseline (56.463 us; speedup 1.0000x reference)
//
#include <hip/hip_runtime.h>
#include <cstdint>
#include <cstddef>

typedef unsigned long long u64;
typedef unsigned int u32;

// Problem constants (from reference)
constexpr int N    = 50000;   // library size
constexpr int D    = 768;     // vision dim
constexpr int OD   = 384;     // option / answer dim
constexpr int TOPK = 25;

// K1 config: one 64-lane wave per row-pair (measured at HBM floor, ~25 us)
constexpr int K1_BLOCKS  = 2048;
constexpr int K1_THREADS = 256;                            // 4 waves
constexpr int WAVES_TOTAL = K1_BLOCKS * (K1_THREADS / 64); // 8192

// k_finish pass geometry: 50000 f32 = 12500 float4; 12*1024 burst + 212 tail
constexpr int N4    = 12500;
constexpr int BURST = 12;
constexpr int TAIL4 = N4 - BURST * 1024;   // 212
constexpr int CAP   = 4096;

// Histogram bin: float bits >> 20. s in [0,1] -> bits <= 0x3F800000 ->
// bin <= 0x3F8 = 1016 < 1024.
constexpr int BINSHIFT = 20;

// ---------------------------------------------------------------------------
// K1: per-row cosine score s[n] = clip(dot(v,f_n)/(|v||f_n|), 0, 1),
//     per-block exp-partials, AND a 1024-bin histogram of score bits>>20
//     (LDS-accumulated, merged to global with one atomicAdd per nonzero bin;
//     ~24 rows/block -> <=24 nonzero bins -> ~49K distributed atomics total,
//     fire-and-forget, hidden under the memory-bound loop).
// Score math byte-identical to rounds 3-8 (absmax 0.0).
// ---------------------------------------------------------------------------
__global__ __launch_bounds__(K1_THREADS)
void k_scores(const float* __restrict__ v,
              const float* __restrict__ n_feats,
              float* __restrict__ s_out,
              float* __restrict__ part_out,
              u32*   __restrict__ ghist)     // 1024 u32, zeroed per call
{
    const int lane  = threadIdx.x & 63;
    const int wib   = threadIdx.x >> 6;           // wave in block (0..3)
    const int gwave = blockIdx.x * 4 + wib;       // global wave id

    __shared__ u32 bhist[1024];
    for (int i = threadIdx.x; i < 1024; i += K1_THREADS) bhist[i] = 0u;
    __syncthreads();

    const float4* v4 = reinterpret_cast<const float4*>(v);
    const float4 va = v4[lane];
    const float4 vb = v4[lane + 64];
    const float4 vc = v4[lane + 128];

    float vsq = 0.f;
    vsq = fmaf(va.x, va.x, vsq); vsq = fmaf(va.y, va.y, vsq);
    vsq = fmaf(va.z, va.z, vsq); vsq = fmaf(va.w, va.w, vsq);
    vsq = fmaf(vb.x, vb.x, vsq); vsq = fmaf(vb.y, vb.y, vsq);
    vsq = fmaf(vb.z, vb.z, vsq); vsq = fmaf(vb.w, vb.w, vsq);
    vsq = fmaf(vc.x, vc.x, vsq); vsq = fmaf(vc.y, vc.y, vsq);
    vsq = fmaf(vc.z, vc.z, vsq); vsq = fmaf(vc.w, vc.w, vsq);
    #pragma unroll
    for (int off = 32; off; off >>= 1) vsq += __shfl_xor(vsq, off);
    const float inv_vn = 1.0f / fmaxf(sqrtf(vsq), 1e-12f);

    float esum = 0.f;
    for (int r = 2 * gwave; r < N; r += 2 * WAVES_TOTAL) {
        // N is even: r+1 < N always
        const float4* f0 = reinterpret_cast<const float4*>(n_feats + (size_t)r * D);
        const float4* f1 = reinterpret_cast<const float4*>(n_feats + (size_t)(r + 1) * D);
        const float4 a0 = f0[lane];
        const float4 a1 = f0[lane + 64];
        const float4 a2 = f0[lane + 128];
        const float4 b0 = f1[lane];
        const float4 b1 = f1[lane + 64];
        const float4 b2 = f1[lane + 128];

        float dA = 0.f, nA = 0.f, dB = 0.f, nB = 0.f;
        dA = fmaf(a0.x, va.x, dA); nA = fmaf(a0.x, a0.x, nA);
        dB = fmaf(b0.x, va.x, dB); nB = fmaf(b0.x, b0.x, nB);
        dA = fmaf(a0.y, va.y, dA); nA = fmaf(a0.y, a0.y, nA);
        dB = fmaf(b0.y, va.y, dB); nB = fmaf(b0.y, b0.y, nB);
        dA = fmaf(a0.z, va.z, dA); nA = fmaf(a0.z, a0.z, nA);
        dB = fmaf(b0.z, va.z, dB); nB = fmaf(b0.z, b0.z, nB);
        dA = fmaf(a0.w, va.w, dA); nA = fmaf(a0.w, a0.w, nA);
        dB = fmaf(b0.w, va.w, dB); nB = fmaf(b0.w, b0.w, nB);
        dA = fmaf(a1.x, vb.x, dA); nA = fmaf(a1.x, a1.x, nA);
        dB = fmaf(b1.x, vb.x, dB); nB = fmaf(b1.x, b1.x, nB);
        dA = fmaf(a1.y, vb.y, dA); nA = fmaf(a1.y, a1.y, nA);
        dB = fmaf(b1.y, vb.y, dB); nB = fmaf(b1.y, b1.y, nB);
        dA = fmaf(a1.z, vb.z, dA); nA = fmaf(a1.z, a1.z, nA);
        dB = fmaf(b1.z, vb.z, dB); nB = fmaf(b1.z, b1.z, nB);
        dA = fmaf(a1.w, vb.w, dA); nA = fmaf(a1.w, a1.w, nA);
        dB = fmaf(b1.w, vb.w, dB); nB = fmaf(b1.w, b1.w, nB);
        dA = fmaf(a2.x, vc.x, dA); nA = fmaf(a2.x, a2.x, nA);
        dB = fmaf(b2.x, vc.x, dB); nB = fmaf(b2.x, b2.x, nB);
        dA = fmaf(a2.y, vc.y, dA); nA = fmaf(a2.y, a2.y, nA);
        dB = fmaf(b2.y, vc.y, dB); nB = fmaf(b2.y, b2.y, nB);
        dA = fmaf(a2.z, vc.z, dA); nA = fmaf(a2.z, a2.z, nA);
        dB = fmaf(b2.z, vc.z, dB); nB = fmaf(b2.z, b2.z, nB);
        dA = fmaf(a2.w, vc.w, dA); nA = fmaf(a2.w, a2.w, nA);
        dB = fmaf(b2.w, vc.w, dB); nB = fmaf(b2.w, b2.w, nB);

        #pragma unroll
        for (int off = 32; off; off >>= 1) {
            dA += __shfl_xor(dA, off);
            nA += __shfl_xor(nA, off);
            dB += __shfl_xor(dB, off);
            nB += __shfl_xor(nB, off);
        }

        float sA = dA * inv_vn / fmaxf(sqrtf(nA), 1e-12f);
        sA = fminf(fmaxf(sA, 0.f), 1.f);
        float sB = dB * inv_vn / fmaxf(sqrtf(nB), 1e-12f);
        sB = fminf(fmaxf(sB, 0.f), 1.f);
        if (lane == 0) {
            float2 sv; sv.x = sA; sv.y = sB;      // r even -> 8B aligned
            *reinterpret_cast<float2*>(s_out + r) = sv;
            const u32 ba = __float_as_uint(sA);
            const u32 bb = __float_as_uint(sB);
            if (ba) atomicAdd(&bhist[ba >> BINSHIFT], 1u);
            if (bb) atomicAdd(&bhist[bb >> BINSHIFT], 1u);
        }
        esum += expf(sA) + expf(sB);
    }

    __shared__ float wsum[4];
    if (lane == 0) wsum[wib] = esum;
    __syncthreads();   // also orders all bhist atomics before the merge below
    if (threadIdx.x == 0)
        part_out[blockIdx.x] = (wsum[0] + wsum[1]) + (wsum[2] + wsum[3]);

    for (int i = threadIdx.x; i < 1024; i += K1_THREADS) {
        const u32 c = bhist[i];
        if (c) atomicAdd(&ghist[i], c);   // device-scope, no cache maintenance
    }
}

// ---------------------------------------------------------------------------
// K2: ONE block, 1024 threads. Single-scan select (histogram prebuilt by K1):
//  (a) burst-load ALL 200KB of scores into registers (48+ VGPR, stays live)
//  (b) Z = tree over part[2048]; load ghist -> LDS
//  (c) ping-pong suffix scan -> crossing bin b1 (cum count >= 25)
//  (d) compact keys with bin >= b1 from REGISTERS (no reload) -> L
//  (e) rank-sort L (LDS broadcast reads) -> exact jax-ordered top-25
//  (f) oia gather + 3 dots in one packed tree
// ---------------------------------------------------------------------------
__global__ __launch_bounds__(1024)
void k_finish(const float4* __restrict__ s4,
              const float* __restrict__ part,
              const u32*  __restrict__ ghist,
              const float* __restrict__ n_answ,
              const float* __restrict__ o,
              const float* __restrict__ temp_vid,
              float* __restrict__ out)
{
    __shared__ u32   hh[1024];
    __shared__ u32   ss[1024];
    __shared__ float redA[1024], redB[1024], redC[1024];
    __shared__ u64   L[CAP];         // 32 KB
    __shared__ float topw[TOPK];
    __shared__ int   topi[TOPK];
    __shared__ u32   ctrL;
    __shared__ int   b1sh;
    __shared__ float zsh;

    const int tid = threadIdx.x;

    // (a) burst-load scores into registers (issued first; in flight under (b))
    float4 r[BURST];
    #pragma unroll
    for (int j = 0; j < BURST; ++j) r[j] = s4[tid + j * 1024];
    float4 rt = make_float4(0.f, 0.f, 0.f, 0.f);
    if (tid < TAIL4) rt = s4[BURST * 1024 + tid];

    // (b) hist load + Z tree
    hh[tid]   = ghist[tid];
    redA[tid] = part[tid] + part[tid + 1024];
    if (tid == 0) { ctrL = 0; b1sh = 0; }
    __syncthreads();
    for (int s = 512; s > 0; s >>= 1) {
        if (tid < s) redA[tid] += redA[tid + s];
        __syncthreads();
    }
    if (tid == 0) zsh = redA[0];

    // (c) suffix scan (ping-pong); 10 swaps (even) -> result back in hh
    {
        u32* src = hh;
        u32* dst = ss;
        for (int st = 1; st < 1024; st <<= 1) {
            dst[tid] = src[tid] + ((tid + st < 1024) ? src[tid + st] : 0u);
            __syncthreads();
            u32* t_ = src; src = dst; dst = t_;
        }
        if (src[tid] >= (u32)TOPK && (tid == 1023 || src[tid + 1] < (u32)TOPK))
            b1sh = tid;                              // exactly one thread
    }
    __syncthreads();
    const int b1 = b1sh;

    // (d) compact bin >= b1 straight from registers.
    // key = (valbits<<32)|(~idx): value desc, ties -> lower index (jax order)
    auto append = [&](u32 b, int e) {
        if (b && (int)(b >> BINSHIFT) >= b1) {
            const u32 p = atomicAdd(&ctrL, 1u);
            if (p < (u32)CAP)
                L[p] = ((u64)b << 32) | (u64)(0xFFFFFFFFu - (u32)e);
        }
    };
    #pragma unroll
    for (int j = 0; j < BURST; ++j) {
        const int e = (tid + j * 1024) * 4;
        append(__float_as_uint(r[j].x), e + 0);
        append(__float_as_uint(r[j].y), e + 1);
        append(__float_as_uint(r[j].z), e + 2);
        append(__float_as_uint(r[j].w), e + 3);
    }
    if (tid < TAIL4) {
        const int e = (BURST * 1024 + tid) * 4;
        append(__float_as_uint(rt.x), e + 0);
        append(__float_as_uint(rt.y), e + 1);
        append(__float_as_uint(rt.z), e + 2);
        append(__float_as_uint(rt.w), e + 3);
    }
    __syncthreads();

    // (e) rank-sort L (unique keys -> unique ranks); ctrL >= 25 by b1 constr.
    const int nL = (int)((ctrL < (u32)CAP) ? ctrL : (u32)CAP);
    for (int i = tid; i < nL; i += 1024) {
        const u64 ki = L[i];
        int rk = 0;
        for (int j = 0; j < nL; ++j) rk += (L[j] > ki);   // LDS broadcast reads
        if (rk < TOPK) {
            topw[rk] = expf(__uint_as_float((u32)(ki >> 32)));
            topi[rk] = (int)(0xFFFFFFFFu - (u32)(ki & 0xFFFFFFFFu));
        }
    }
    __syncthreads();

    // (f) oia gather + 3 dots.  attention_j = exp(s_j)/Z * 2*sigmoid(temp)
    const float gate  = 2.f / (1.f + expf(-temp_vid[0]));
    const float scale = gate / zsh;
    float oia_ = 0.f;
    if (tid < OD) {
        #pragma unroll
        for (int j = 0; j < TOPK; ++j)
            oia_ = fmaf(topw[j] * scale, n_answ[(size_t)topi[j] * OD + tid], oia_);
    }
    redA[tid] = (tid < OD) ? oia_ * o[tid]          : 0.f;
    redB[tid] = (tid < OD) ? oia_ * o[OD + tid]     : 0.f;
    redC[tid] = (tid < OD) ? oia_ * o[2 * OD + tid] : 0.f;
    __syncthreads();
    for (int s = 512; s > 0; s >>= 1) {
        if (tid < s) {
            redA[tid] += redA[tid + s];
            redB[tid] += redB[tid + s];
            redC[tid] += redC[tid + s];
        }
        __syncthreads();
    }
    if (tid == 0) { out[0] = redA[0]; out[1] = redB[0]; out[2] = redC[0]; }
}

// ---------------------------------------------------------------------------
extern "C" void kernel_launch(void* const* d_in, const int* in_sizes, int n_in,
                              void* d_out, int out_size, void* d_ws, size_t ws_size,
                              hipStream_t stream)
{
    // setup_inputs order:
    // 0 v, 1 n_feats, 2 aud, 3 n_auds, 4 ocr, 5 n_ocrs, 6 o, 7 n_answ,
    // 8 temp_vid, 9 temp_aud, 10 temp_ocr
    const float* v        = (const float*)d_in[0];
    const float* n_feats  = (const float*)d_in[1];
    const float* o        = (const float*)d_in[6];
    const float* n_answ   = (const float*)d_in[7];
    const float* temp_vid = (const float*)d_in[8];
    // aud/ocr branches are multiplied by exactly 0.0 in the reference -> skipped.
    float* out = (float*)d_out;

    char* ws = (char*)d_ws;
    float* ws_s    = (float*)(ws);           // 50000 f32 = 200000 B (16B aligned)
    float* ws_part = (float*)(ws + 200704);  // 2048 f32  = 8192 B
    u32*   ws_hist = (u32*)  (ws + 208896);  // 1024 u32  = 4096 B

    hipMemsetAsync(ws_hist, 0, 4096, stream);   // async, graph-capturable
    k_scores<<<K1_BLOCKS, K1_THREADS, 0, stream>>>(v, n_feats, ws_s, ws_part,
                                                   ws_hist);
    k_finish<<<1, 1024, 0, stream>>>((const float4*)ws_s, ws_part, ws_hist,
                                     n_answ, o, temp_vid, out);
}

// Round 11
// 41.889 us; speedup vs baseline: 1.3479x; 1.3479x over previous
//
#include <hip/hip_runtime.h>
#include <cstdint>
#include <cstddef>

typedef unsigned long long u64;
typedef unsigned int u32;

// Problem constants (from reference)
constexpr int N    = 50000;   // library size
constexpr int D    = 768;     // vision dim
constexpr int OD   = 384;     // option / answer dim
constexpr int TOPK = 25;

// K1 config: one 64-lane wave per row-pair (proven at HBM floor, rounds 3/5/6/8)
constexpr int K1_BLOCKS  = 2048;
constexpr int K1_THREADS = 256;                            // 4 waves
constexpr int WAVES_TOTAL = K1_BLOCKS * (K1_THREADS / 64); // 8192

// k_finish pass geometry: 50000 f32 = 12500 float4; 12*1024 burst + 212 tail
constexpr int N4    = 12500;
constexpr int BURST = 12;
constexpr int TAIL4 = N4 - BURST * 1024;   // 212
constexpr int CAP   = 4096;

// Histogram bin: float bits >> 20. s in [0,1] -> bits <= 0x3F800000 ->
// bin <= 0x3F8 = 1016 < 1024.
constexpr int BINSHIFT = 20;

// ---------------------------------------------------------------------------
// K1: per-row cosine score s[n] = clip(dot(v,f_n)/(|v||f_n|), 0, 1),
//     plus per-block partial sums of exp(s[n]) (softmax denominator).
// Measured at the 153.6MB HBM floor (~25 us, ~97% of achievable read BW).
// Structure ledger (why this is two plain kernels): R4 in-kernel grid sync
// +296us (L2 writeback storm); R9 relaxed-atomic fusion +12.6us; R10
// histogram-in-K1 +14.8us. Kernel boundary = ONE L2 flush; cheapest option.
// ---------------------------------------------------------------------------
__global__ __launch_bounds__(K1_THREADS)
void k_scores(const float* __restrict__ v,
              const float* __restrict__ n_feats,
              float* __restrict__ s_out,
              float* __restrict__ part_out)
{
    const int lane  = threadIdx.x & 63;
    const int wib   = threadIdx.x >> 6;           // wave in block (0..3)
    const int gwave = blockIdx.x * 4 + wib;       // global wave id

    const float4* v4 = reinterpret_cast<const float4*>(v);
    const float4 va = v4[lane];
    const float4 vb = v4[lane + 64];
    const float4 vc = v4[lane + 128];

    float vsq = 0.f;
    vsq = fmaf(va.x, va.x, vsq); vsq = fmaf(va.y, va.y, vsq);
    vsq = fmaf(va.z, va.z, vsq); vsq = fmaf(va.w, va.w, vsq);
    vsq = fmaf(vb.x, vb.x, vsq); vsq = fmaf(vb.y, vb.y, vsq);
    vsq = fmaf(vb.z, vb.z, vsq); vsq = fmaf(vb.w, vb.w, vsq);
    vsq = fmaf(vc.x, vc.x, vsq); vsq = fmaf(vc.y, vc.y, vsq);
    vsq = fmaf(vc.w, vc.w, vsq); vsq = fmaf(vc.z, vc.z, vsq);
    #pragma unroll
    for (int off = 32; off; off >>= 1) vsq += __shfl_xor(vsq, off);
    const float inv_vn = 1.0f / fmaxf(sqrtf(vsq), 1e-12f);

    float esum = 0.f;
    for (int r = 2 * gwave; r < N; r += 2 * WAVES_TOTAL) {
        // N is even: r+1 < N always
        const float4* f0 = reinterpret_cast<const float4*>(n_feats + (size_t)r * D);
        const float4* f1 = reinterpret_cast<const float4*>(n_feats + (size_t)(r + 1) * D);
        const float4 a0 = f0[lane];
        const float4 a1 = f0[lane + 64];
        const float4 a2 = f0[lane + 128];
        const float4 b0 = f1[lane];
        const float4 b1 = f1[lane + 64];
        const float4 b2 = f1[lane + 128];

        float dA = 0.f, nA = 0.f, dB = 0.f, nB = 0.f;
        dA = fmaf(a0.x, va.x, dA); nA = fmaf(a0.x, a0.x, nA);
        dB = fmaf(b0.x, va.x, dB); nB = fmaf(b0.x, b0.x, nB);
        dA = fmaf(a0.y, va.y, dA); nA = fmaf(a0.y, a0.y, nA);
        dB = fmaf(b0.y, va.y, dB); nB = fmaf(b0.y, b0.y, nB);
        dA = fmaf(a0.z, va.z, dA); nA = fmaf(a0.z, a0.z, nA);
        dB = fmaf(b0.z, va.z, dB); nB = fmaf(b0.z, b0.z, nB);
        dA = fmaf(a0.w, va.w, dA); nA = fmaf(a0.w, a0.w, nA);
        dB = fmaf(b0.w, va.w, dB); nB = fmaf(b0.w, b0.w, nB);
        dA = fmaf(a1.x, vb.x, dA); nA = fmaf(a1.x, a1.x, nA);
        dB = fmaf(b1.x, vb.x, dB); nB = fmaf(b1.x, b1.x, nB);
        dA = fmaf(a1.y, vb.y, dA); nA = fmaf(a1.y, a1.y, nA);
        dB = fmaf(b1.y, vb.y, dB); nB = fmaf(b1.y, b1.y, nB);
        dA = fmaf(a1.z, vb.z, dA); nA = fmaf(a1.z, a1.z, nA);
        dB = fmaf(b1.z, vb.z, dB); nB = fmaf(b1.z, b1.z, nB);
        dA = fmaf(a1.w, vb.w, dA); nA = fmaf(a1.w, a1.w, nA);
        dB = fmaf(b1.w, vb.w, dB); nB = fmaf(b1.w, b1.w, nB);
        dA = fmaf(a2.x, vc.x, dA); nA = fmaf(a2.x, a2.x, nA);
        dB = fmaf(b2.x, vc.x, dB); nB = fmaf(b2.x, b2.x, nB);
        dA = fmaf(a2.y, vc.y, dA); nA = fmaf(a2.y, a2.y, nA);
        dB = fmaf(b2.y, vc.y, dB); nB = fmaf(b2.y, b2.y, nB);
        dA = fmaf(a2.z, vc.z, dA); nA = fmaf(a2.z, a2.z, nA);
        dB = fmaf(b2.z, vc.z, dB); nB = fmaf(b2.z, b2.z, nB);
        dA = fmaf(a2.w, vc.w, dA); nA = fmaf(a2.w, a2.w, nA);
        dB = fmaf(b2.w, vc.w, dB); nB = fmaf(b2.w, b2.w, nB);

        #pragma unroll
        for (int off = 32; off; off >>= 1) {
            dA += __shfl_xor(dA, off);
            nA += __shfl_xor(nA, off);
            dB += __shfl_xor(dB, off);
            nB += __shfl_xor(nB, off);
        }

        float sA = dA * inv_vn / fmaxf(sqrtf(nA), 1e-12f);
        sA = fminf(fmaxf(sA, 0.f), 1.f);
        float sB = dB * inv_vn / fmaxf(sqrtf(nB), 1e-12f);
        sB = fminf(fmaxf(sB, 0.f), 1.f);
        if (lane == 0) {
            float2 sv; sv.x = sA; sv.y = sB;      // r even -> 8B aligned
            *reinterpret_cast<float2*>(s_out + r) = sv;
        }
        esum += expf(sA) + expf(sB);
    }

    __shared__ float wsum[4];
    if (lane == 0) wsum[wib] = esum;
    __syncthreads();
    if (threadIdx.x == 0)
        part_out[blockIdx.x] = (wsum[0] + wsum[1]) + (wsum[2] + wsum[3]);
}

// ---------------------------------------------------------------------------
// K2: ONE block, 1024 threads. Latency-hidden radix-select:
//  (a) Z = sum of 2048 exp-partials
//  (b) pass 1 (12-deep float4 burst, ~200 KB in flight): 1024-bin histogram
//      of float bits>>20 (s<=1.0 -> bin<=1016). Zeros (clip) skipped —
//      assumes >=25 positive scores (~25000 here).
//  (c) ping-pong suffix scan -> crossing bin b1 (cum count >= 25)
//  (d) pass 2 (burst): compact ALL keys with bin >= b1 into L (expected
//      ~50, cap 4096). key = (valbits<<32)|(~idx): value desc, ties -> lower
//      index (matches jax.lax.top_k; only the top-25 SET matters anyway).
//  (e) rank-sort L via LDS broadcast reads -> exact top-25, deterministic.
//  (f) oia gather + 3 dots in one packed tree.
// ---------------------------------------------------------------------------
__global__ __launch_bounds__(1024)
void k_finish(const float4* __restrict__ s4,
              const float* __restrict__ part,
              const float* __restrict__ n_answ,
              const float* __restrict__ o,
              const float* __restrict__ temp_vid,
              float* __restrict__ out)
{
    __shared__ u32   hist[1024];
    __shared__ u32   sufb[1024];
    __shared__ float redA[1024], redB[1024], redC[1024];
    __shared__ u64   L[CAP];         // 32 KB
    __shared__ u64   Ls[TOPK];
    __shared__ float topw[TOPK];
    __shared__ int   topi[TOPK];
    __shared__ u32   ctrL;
    __shared__ int   b1sh;
    __shared__ float zsh;

    const int tid = threadIdx.x;

    // (a) Z over part[2048] (redA as scratch)
    redA[tid] = part[tid] + part[tid + 1024];
    hist[tid] = 0;
    if (tid == 0) { ctrL = 0; b1sh = 0; }
    __syncthreads();
    for (int s = 512; s > 0; s >>= 1) {
        if (tid < s) redA[tid] += redA[tid + s];
        __syncthreads();
    }
    if (tid == 0) zsh = redA[0];

    // (b) pass 1: histogram, burst-loaded (all 12 loads in flight per thread)
    {
        float4 r[BURST];
        #pragma unroll
        for (int j = 0; j < BURST; ++j) r[j] = s4[tid + j * 1024];
        float4 rt;
        if (tid < TAIL4) rt = s4[BURST * 1024 + tid];

        #pragma unroll
        for (int j = 0; j < BURST; ++j) {
            u32 b;
            b = __float_as_uint(r[j].x); if (b) atomicAdd(&hist[b >> BINSHIFT], 1u);
            b = __float_as_uint(r[j].y); if (b) atomicAdd(&hist[b >> BINSHIFT], 1u);
            b = __float_as_uint(r[j].z); if (b) atomicAdd(&hist[b >> BINSHIFT], 1u);
            b = __float_as_uint(r[j].w); if (b) atomicAdd(&hist[b >> BINSHIFT], 1u);
        }
        if (tid < TAIL4) {
            u32 b;
            b = __float_as_uint(rt.x); if (b) atomicAdd(&hist[b >> BINSHIFT], 1u);
            b = __float_as_uint(rt.y); if (b) atomicAdd(&hist[b >> BINSHIFT], 1u);
            b = __float_as_uint(rt.z); if (b) atomicAdd(&hist[b >> BINSHIFT], 1u);
            b = __float_as_uint(rt.w); if (b) atomicAdd(&hist[b >> BINSHIFT], 1u);
        }
    }
    __syncthreads();

    // (c) suffix scan (ping-pong, one barrier per step); result lands in hist
    {
        u32* src = hist;
        u32* dst = sufb;
        for (int s = 1; s < 1024; s <<= 1) {
            dst[tid] = src[tid] + ((tid + s < 1024) ? src[tid + s] : 0u);
            __syncthreads();
            u32* t_ = src; src = dst; dst = t_;
        }
        // 10 swaps (even) -> src == hist holds the suffix sums
        if (src[tid] >= (u32)TOPK && (tid == 1023 || src[tid + 1] < (u32)TOPK))
            b1sh = tid;                              // exactly one thread
    }
    __syncthreads();
    const int b1 = b1sh;

    // (d) pass 2: compact bin >= b1 (reads now cache-hot)
    {
        float4 r[BURST];
        #pragma unroll
        for (int j = 0; j < BURST; ++j) r[j] = s4[tid + j * 1024];
        float4 rt;
        if (tid < TAIL4) rt = s4[BURST * 1024 + tid];

        #pragma unroll
        for (int j = 0; j < BURST; ++j) {
            const int base = (tid + j * 1024) * 4;
            u32 b;
            b = __float_as_uint(r[j].x);
            if (b && (int)(b >> BINSHIFT) >= b1) { u32 p = atomicAdd(&ctrL, 1u); if (p < CAP) L[p] = ((u64)b << 32) | (u64)(0xFFFFFFFFu - (u32)(base + 0)); }
            b = __float_as_uint(r[j].y);
            if (b && (int)(b >> BINSHIFT) >= b1) { u32 p = atomicAdd(&ctrL, 1u); if (p < CAP) L[p] = ((u64)b << 32) | (u64)(0xFFFFFFFFu - (u32)(base + 1)); }
            b = __float_as_uint(r[j].z);
            if (b && (int)(b >> BINSHIFT) >= b1) { u32 p = atomicAdd(&ctrL, 1u); if (p < CAP) L[p] = ((u64)b << 32) | (u64)(0xFFFFFFFFu - (u32)(base + 2)); }
            b = __float_as_uint(r[j].w);
            if (b && (int)(b >> BINSHIFT) >= b1) { u32 p = atomicAdd(&ctrL, 1u); if (p < CAP) L[p] = ((u64)b << 32) | (u64)(0xFFFFFFFFu - (u32)(base + 3)); }
        }
        if (tid < TAIL4) {
            const int base = (BURST * 1024 + tid) * 4;
            u32 b;
            b = __float_as_uint(rt.x);
            if (b && (int)(b >> BINSHIFT) >= b1) { u32 p = atomicAdd(&ctrL, 1u); if (p < CAP) L[p] = ((u64)b << 32) | (u64)(0xFFFFFFFFu - (u32)(base + 0)); }
            b = __float_as_uint(rt.y);
            if (b && (int)(b >> BINSHIFT) >= b1) { u32 p = atomicAdd(&ctrL, 1u); if (p < CAP) L[p] = ((u64)b << 32) | (u64)(0xFFFFFFFFu - (u32)(base + 1)); }
            b = __float_as_uint(rt.z);
            if (b && (int)(b >> BINSHIFT) >= b1) { u32 p = atomicAdd(&ctrL, 1u); if (p < CAP) L[p] = ((u64)b << 32) | (u64)(0xFFFFFFFFu - (u32)(base + 2)); }
            b = __float_as_uint(rt.w);
            if (b && (int)(b >> BINSHIFT) >= b1) { u32 p = atomicAdd(&ctrL, 1u); if (p < CAP) L[p] = ((u64)b << 32) | (u64)(0xFFFFFFFFu - (u32)(base + 3)); }
        }
    }
    __syncthreads();

    // (e) rank-sort L (unique keys -> unique ranks); keep ranks < 25.
    // ctrL >= 25 by construction of b1 (suffix count at b1 >= TOPK).
    const int nL = (int)((ctrL < (u32)CAP) ? ctrL : (u32)CAP);
    for (int i = tid; i < nL; i += 1024) {
        const u64 ki = L[i];
        int rank = 0;
        for (int j = 0; j < nL; ++j) rank += (L[j] > ki);   // LDS broadcast reads
        if (rank < TOPK) Ls[rank] = ki;
    }
    __syncthreads();

    if (tid < TOPK) {
        const u64 kk = Ls[tid];
        topw[tid] = expf(__uint_as_float((u32)(kk >> 32)));
        topi[tid] = (int)(0xFFFFFFFFu - (u32)(kk & 0xFFFFFFFFu));
    }
    __syncthreads();

    // (f) oia gather + 3 dots.  attention_j = exp(s_j)/Z * 2*sigmoid(temp)
    const float gate  = 2.f / (1.f + expf(-temp_vid[0]));
    const float scale = gate / zsh;
    float oia_ = 0.f;
    if (tid < OD) {
        #pragma unroll
        for (int j = 0; j < TOPK; ++j)
            oia_ = fmaf(topw[j] * scale, n_answ[(size_t)topi[j] * OD + tid], oia_);
    }
    redA[tid] = (tid < OD) ? oia_ * o[0 * OD + tid] : 0.f;
    redB[tid] = (tid < OD) ? oia_ * o[1 * OD + tid] : 0.f;
    redC[tid] = (tid < OD) ? oia_ * o[2 * OD + tid] : 0.f;
    __syncthreads();
    for (int s = 512; s > 0; s >>= 1) {
        if (tid < s) {
            redA[tid] += redA[tid + s];
            redB[tid] += redB[tid + s];
            redC[tid] += redC[tid + s];
        }
        __syncthreads();
    }
    if (tid == 0) { out[0] = redA[0]; out[1] = redB[0]; out[2] = redC[0]; }
}

// ---------------------------------------------------------------------------
extern "C" void kernel_launch(void* const* d_in, const int* in_sizes, int n_in,
                              void* d_out, int out_size, void* d_ws, size_t ws_size,
                              hipStream_t stream)
{
    // setup_inputs order:
    // 0 v, 1 n_feats, 2 aud, 3 n_auds, 4 ocr, 5 n_ocrs, 6 o, 7 n_answ,
    // 8 temp_vid, 9 temp_aud, 10 temp_ocr
    const float* v        = (const float*)d_in[0];
    const float* n_feats  = (const float*)d_in[1];
    const float* o        = (const float*)d_in[6];
    const float* n_answ   = (const float*)d_in[7];
    const float* temp_vid = (const float*)d_in[8];
    // aud/ocr branches are multiplied by exactly 0.0 in the reference -> skipped.
    float* out = (float*)d_out;

    char* ws = (char*)d_ws;
    float* ws_s    = (float*)(ws);           // 50000 f32 = 200000 B (16B aligned)
    float* ws_part = (float*)(ws + 200704);  // 2048 f32  = 8192 B

    k_scores<<<K1_BLOCKS, K1_THREADS, 0, stream>>>(v, n_feats, ws_s, ws_part);
    k_finish<<<1, 1024, 0, stream>>>((const float4*)ws_s, ws_part, n_answ, o,
                                     temp_vid, out);
}